// Round 21
// baseline (89.623 us; speedup 1.0000x reference)
//
#include <hip/hip_runtime.h>
#include <math.h>

using f32x4  = __attribute__((ext_vector_type(4))) float;
using bf16x8 = __attribute__((ext_vector_type(8))) short;

constexpr int kB = 4, kC = 256, kL = 2048, kH = 8;
constexpr float kQScale = 0.25505402264f;  // 1/sqrt(32) * log2(e)

__device__ __forceinline__ unsigned short f2bf(float f) {
    unsigned u = __builtin_bit_cast(unsigned, f);
    u += 0x7fffu + ((u >> 16) & 1u);
    return (unsigned short)(u >> 16);
}
__device__ __forceinline__ unsigned cvt_pk(float lo, float hi) {
    unsigned r;
    asm("v_cvt_pk_bf16_f32 %0, %1, %2" : "=v"(r) : "v"(lo), "v"(hi));
    return r;
}
__device__ __forceinline__ f32x4 mfma16(bf16x8 a, bf16x8 b, f32x4 c) {
    return __builtin_amdgcn_mfma_f32_16x16x32_bf16(a, b, c, 0, 0, 0);
}
__device__ __forceinline__ bf16x8 bc8(unsigned a, unsigned b, unsigned c, unsigned d) {
    return __builtin_bit_cast(bf16x8, make_uint4(a, b, c, d));
}
// async global->LDS, 16B per lane; LDS dest = base + lane*16 (HW-linear).
__device__ __forceinline__ void glds16(const unsigned short* g, unsigned short* l) {
    __builtin_amdgcn_global_load_lds(
        (const __attribute__((address_space(1))) unsigned int*)g,
        (__attribute__((address_space(3))) unsigned int*)l, 16, 0, 0);
}

// ---------------------------------------------------------------------------
// Fused GN (blocks 0..127) + weight cvt (blocks 128..383): one launch stage.
// ---------------------------------------------------------------------------
__global__ __launch_bounds__(256) void gncvt_kernel(const float* __restrict__ x,
                                                    const float* __restrict__ gw,
                                                    const float* __restrict__ gb,
                                                    unsigned short* __restrict__ hT,
                                                    const float* __restrict__ qkvw,
                                                    const float* __restrict__ outw,
                                                    unsigned short* __restrict__ wq,
                                                    unsigned short* __restrict__ wo) {
    if (blockIdx.x >= 128) {  // ---- cvt role ----
        int i = (blockIdx.x - 128) * 256 + threadIdx.x;  // 0..65535 float4s
        const float* s; unsigned short* d; int j;
        if (i < 49152) { s = qkvw; d = wq; j = i; }
        else           { s = outw; d = wo; j = i - 49152; }
        float4 v = ((const float4*)s)[j];
        ((uint2*)d)[j] = make_uint2(cvt_pk(v.x, v.y), cvt_pk(v.z, v.w));
        return;
    }
    // ---- groupnorm role ----
    int b = blockIdx.x >> 5, g = blockIdx.x & 31;
    int t = threadIdx.x;
    const float* xp = x + ((size_t)b * kC + g * 8) * kL + 8 * t;

    float v[8][8];
    float s = 0.f, ss = 0.f;
#pragma unroll
    for (int c = 0; c < 8; ++c) {
        float4 a  = *(const float4*)(xp + (size_t)c * kL);
        float4 a2 = *(const float4*)(xp + (size_t)c * kL + 4);
        v[c][0]=a.x; v[c][1]=a.y; v[c][2]=a.z; v[c][3]=a.w;
        v[c][4]=a2.x; v[c][5]=a2.y; v[c][6]=a2.z; v[c][7]=a2.w;
        s  += (a.x+a.y)+(a.z+a.w)+(a2.x+a2.y)+(a2.z+a2.w);
        ss += a.x*a.x+a.y*a.y+a.z*a.z+a.w*a.w+a2.x*a2.x+a2.y*a2.y+a2.z*a2.z+a2.w*a2.w;
    }
#pragma unroll
    for (int off = 32; off; off >>= 1) {
        s  += __shfl_down(s, off);
        ss += __shfl_down(ss, off);
    }
    __shared__ float red[8];
    int wv = t >> 6;
    if ((t & 63) == 0) { red[wv] = s; red[4 + wv] = ss; }
    __syncthreads();
    s  = red[0] + red[1] + red[2] + red[3];
    ss = red[4] + red[5] + red[6] + red[7];
    float mean = s * (1.f / 16384.f);
    float var  = ss * (1.f / 16384.f) - mean * mean;
    float rstd = rsqrtf(var + 1e-5f);

    float wc[8], bc[8];
#pragma unroll
    for (int c = 0; c < 8; ++c) { wc[c] = gw[g*8+c] * rstd; bc[c] = gb[g*8+c]; }

    unsigned short* hp = hT + ((size_t)b * kL + 8 * t) * kC + g * 8;
#pragma unroll
    for (int j = 0; j < 8; ++j) {
        unsigned pk[4];
#pragma unroll
        for (int c2 = 0; c2 < 4; ++c2) {
            pk[c2] = cvt_pk((v[2*c2  ][j] - mean) * wc[2*c2  ] + bc[2*c2  ],
                            (v[2*c2+1][j] - mean) * wc[2*c2+1] + bc[2*c2+1]);
        }
        *(uint4*)(hp + (size_t)j * kC) = make_uint4(pk[0], pk[1], pk[2], pk[3]);
    }
}

// ---------------------------------------------------------------------------
// Merged QKV GEMM v2 (r18, unchanged).
// ---------------------------------------------------------------------------
__device__ __forceinline__ void store_qk(unsigned short* __restrict__ base, size_t bh,
                                         int n, int d0, f32x4 acc,
                                         const float* bias4, float scale) {
    float v0 = (acc[0] + bias4[0]) * scale, v1 = (acc[1] + bias4[1]) * scale;
    float v2 = (acc[2] + bias4[2]) * scale, v3 = (acc[3] + bias4[3]) * scale;
    *(uint2*)(base + (bh * kL + n) * 32 + d0) = make_uint2(cvt_pk(v0, v1), cvt_pk(v2, v3));
}

__global__ __launch_bounds__(256) void qkv_gemm(const unsigned short* __restrict__ Wb,
                                                const unsigned short* __restrict__ hT,
                                                const float* __restrict__ qkvb,
                                                unsigned short* __restrict__ qT,
                                                unsigned short* __restrict__ kT,
                                                unsigned short* __restrict__ vbuf) {
    __shared__ alignas(16) unsigned short Hlds[2][8][512];
    int t = threadIdx.x, wv = t >> 6, ll = t & 15, lg = (t >> 4) & 3;
    int lane = t & 63;
    int n0 = blockIdx.x * 128, o0 = blockIdx.y * 64, b = blockIdx.z;
    int obase = o0 + wv * 16;
    const unsigned short* hb = hT + (size_t)b * kL * kC;

    bf16x8 wf[8];
#pragma unroll
    for (int k = 0; k < 8; ++k)
        wf[k] = *(const bf16x8*)(Wb + (size_t)(obase + ll) * 256 + 32 * k + 8 * lg);
    float bias[4];
#pragma unroll
    for (int r = 0; r < 4; ++r) bias[r] = qkvb[obase + 4 * lg + r];
    int mode = (obase < 256) ? 0 : (obase < 512 ? 1 : 2);
    int d0 = (obase & 31) + 4 * lg;

    const unsigned short* hsrc0 = hb + (size_t)(n0 + 16 * (2 * wv)     + ll) * 256 + 8 * lg;
    const unsigned short* hsrc1 = hb + (size_t)(n0 + 16 * (2 * wv + 1) + ll) * 256 + 8 * lg;

    glds16(hsrc0,      &Hlds[0][2 * wv][0]);
    glds16(hsrc1,      &Hlds[0][2 * wv + 1][0]);
    glds16(hsrc0 + 32, &Hlds[1][2 * wv][0]);
    glds16(hsrc1 + 32, &Hlds[1][2 * wv + 1][0]);
    asm volatile("s_waitcnt vmcnt(2)" ::: "memory");
    __builtin_amdgcn_sched_barrier(0);
    __builtin_amdgcn_s_barrier();

    f32x4 acc[8] = {};
    int cur = 0;
    for (int c = 0; c < 8; ++c) {
        bf16x8 hf[8];
#pragma unroll
        for (int nj = 0; nj < 8; ++nj)
            hf[nj] = *(const bf16x8*)&Hlds[cur][nj][lane * 8];
        asm volatile("s_waitcnt lgkmcnt(0)" ::: "memory");
        __builtin_amdgcn_sched_barrier(0);
        __builtin_amdgcn_s_barrier();

        int kn = ((c + 2) & 7) * 32;
        glds16(hsrc0 + kn, &Hlds[cur][2 * wv][0]);
        glds16(hsrc1 + kn, &Hlds[cur][2 * wv + 1][0]);

        __builtin_amdgcn_s_setprio(1);
#pragma unroll
        for (int nj = 0; nj < 8; ++nj)
            acc[nj] = mfma16(wf[c], hf[nj], acc[nj]);
        __builtin_amdgcn_s_setprio(0);

        asm volatile("s_waitcnt vmcnt(2)" ::: "memory");
        __builtin_amdgcn_sched_barrier(0);
        __builtin_amdgcn_s_barrier();
        cur ^= 1;
    }
    asm volatile("s_waitcnt vmcnt(0)" ::: "memory");

#pragma unroll
    for (int nj = 0; nj < 8; ++nj) {
        int n = n0 + 16 * nj + ll;
        if (mode == 0) {
            store_qk(qT, (size_t)b * kH + (obase >> 5), n, d0, acc[nj], bias, kQScale);
        } else if (mode == 1) {
            store_qk(kT, (size_t)b * kH + ((obase - 256) >> 5), n, d0, acc[nj], bias, 1.f);
        } else {
#pragma unroll
            for (int r = 0; r < 4; ++r) {
                size_t row = (size_t)b * kC + (obase - 512) + 4 * lg + r;
                vbuf[row * kL + n] = f2bf(acc[nj][r] + bias[r]);
            }
        }
    }
}

// ---------------------------------------------------------------------------
// Flash attention v21: LDS-traffic diet. 32 q/wave (KV reads amortize 2x),
// V DIRECT from global (r4-validated per-lane addressing; deletes V LDS read
// + V staging; retired by the publish vmcnt since V is older than the newest
// glds), K-only LDS staging with r17 counted-vmcnt barriers, split-K x2
// across blocks (r16-validated partial/combine, absmax 0.03125).
// Grid 1024 = 4 blocks/CU, tail-free. LDS = K 8KB + Plds 17.4KB = 25.4KB.
// Per-query math (key order, lsum add order, PV tt-order) = r16/r17 verbatim.
// ---------------------------------------------------------------------------
__global__ __launch_bounds__(256) void attn_kernel(const unsigned short* __restrict__ qT,
                                                   const unsigned short* __restrict__ kT,
                                                   const unsigned short* __restrict__ vbuf,
                                                   float* __restrict__ pacc,
                                                   float* __restrict__ plsum) {
    __shared__ alignas(16) unsigned short Klds[2][4][512];  // [buf][mj][frag order]
    __shared__ unsigned Plds[4][32][34];
    int t = threadIdx.x, wv = t >> 6, ll = t & 15, hi = (t >> 4) & 3;
    int lane = t & 63;
    int j = blockIdx.x;
    int bid = (j & 7) * 128 + (j >> 3);   // XCD swizzle: 1024 = 8 x 128, bijective
    int kh = bid & 1;                     // key half
    int qg = (bid >> 1) & 15;             // 128-q group
    int bh = bid >> 5;                    // bh 0..31
    int b = bh >> 3, h = bh & 7;
    const unsigned short* qb = qT + (size_t)bh * kL * 32;
    const unsigned short* kb = kT + (size_t)bh * kL * 32;
    const unsigned short* vb = vbuf + ((size_t)b * kC + h * 32) * kL;
    int nbase = qg * 128 + wv * 32;       // this wave's 32 queries
    int kstart = kh * 1024;               // this block's key half

    bf16x8 qf[2];
#pragma unroll
    for (int nj = 0; nj < 2; ++nj)
        qf[nj] = *(const bf16x8*)(qb + (size_t)(nbase + 16 * nj + ll) * 32 + 8 * hi);

    f32x4 acc[2][2] = {};                 // [nj][dj]
    float lsum[2] = {0.f, 0.f};
    const f32x4 zero = {0.f, 0.f, 0.f, 0.f};

    // K staging source (wave stages sub-tile mj = wv); V per-lane direct offsets
    const unsigned short* ksrc = kb + (size_t)(kstart + 16 * wv + ll) * 32 + 8 * hi;
    const int voff0 = ll * kL + 8 * hi;          // V d=ll row
    const int voff1 = (16 + ll) * kL + 8 * hi;   // V d=16+ll row

    // prologue: stage K tiles 0 and 1 (1 glds each per wave)
    glds16(ksrc, &Klds[0][wv][0]);
    glds16(ksrc + (size_t)64 * 32, &Klds[1][wv][0]);
    asm volatile("s_waitcnt vmcnt(1)" ::: "memory");  // tile 0 landed (own op)
    __builtin_amdgcn_sched_barrier(0);
    __builtin_amdgcn_s_barrier();

    int cur = 0;
    for (int it = 0; it < 16; ++it) {
        int m0 = kstart + it * 64;

        // A: read tile-it K fragments (conflict-free b128)
        bf16x8 ka[4];
#pragma unroll
        for (int mj = 0; mj < 4; ++mj)
            ka[mj] = *(const bf16x8*)&Klds[cur][mj][lane * 8];

        // B: read-barrier -> buf[cur] may be overwritten
        asm volatile("s_waitcnt lgkmcnt(0)" ::: "memory");
        __builtin_amdgcn_sched_barrier(0);
        __builtin_amdgcn_s_barrier();

        // C: issue V loads (direct, L2-resident) + stage K tile it+2
        bf16x8 va[2][2];
#pragma unroll
        for (int tt = 0; tt < 2; ++tt) {
            va[0][tt] = *(const bf16x8*)(vb + voff0 + m0 + 32 * tt);
            va[1][tt] = *(const bf16x8*)(vb + voff1 + m0 + 32 * tt);
        }
        int kn = kstart + ((it + 2) & 15) * 64;   // wraps harmlessly last 2 iters
        glds16(kb + (size_t)(kn + 16 * wv + ll) * 32 + 8 * hi, &Klds[cur][wv][0]);

        // D: QK^T (swapped), exp2, P transpose via Plds (stride 34, conflict-free)
        f32x4 s[4][2];
        __builtin_amdgcn_s_setprio(1);
#pragma unroll
        for (int mj = 0; mj < 4; ++mj)
#pragma unroll
            for (int nj = 0; nj < 2; ++nj)
                s[mj][nj] = mfma16(ka[mj], qf[nj], zero);
        __builtin_amdgcn_s_setprio(0);

#pragma unroll
        for (int mj = 0; mj < 4; ++mj)
#pragma unroll
            for (int nj = 0; nj < 2; ++nj) {
                float p0 = __builtin_amdgcn_exp2f(s[mj][nj][0]);
                float p1 = __builtin_amdgcn_exp2f(s[mj][nj][1]);
                float p2 = __builtin_amdgcn_exp2f(s[mj][nj][2]);
                float p3 = __builtin_amdgcn_exp2f(s[mj][nj][3]);
                lsum[nj] += (p0 + p1) + (p2 + p3);
                *(uint2*)&Plds[wv][16 * nj + ll][8 * mj + 2 * hi] =
                    make_uint2(cvt_pk(p0, p1), cvt_pk(p2, p3));
            }

        bf16x8 pbf[2][2];
#pragma unroll
        for (int nj = 0; nj < 2; ++nj)
#pragma unroll
            for (int tt = 0; tt < 2; ++tt) {
                uint2 lo  = *(uint2*)&Plds[wv][16 * nj + ll][16 * tt + 4 * hi];
                uint2 hi2 = *(uint2*)&Plds[wv][16 * nj + ll][16 * tt + 4 * hi + 2];
                pbf[nj][tt] = bc8(lo.x, lo.y, hi2.x, hi2.y);
            }

        // PV (compiler auto-waits va/pbf deps)
        __builtin_amdgcn_s_setprio(1);
#pragma unroll
        for (int tt = 0; tt < 2; ++tt)
#pragma unroll
            for (int nj = 0; nj < 2; ++nj)
#pragma unroll
                for (int dj = 0; dj < 2; ++dj)
                    acc[nj][dj] = mfma16(va[dj][tt], pbf[nj][tt], acc[nj][dj]);
        __builtin_amdgcn_s_setprio(0);

        // E: publish-barrier; vmcnt(1) retires everything but the newest glds
        //    (prev-iter glds + this iter's V loads are all older -> retired).
        asm volatile("s_waitcnt vmcnt(1)" ::: "memory");
        __builtin_amdgcn_sched_barrier(0);
        __builtin_amdgcn_s_barrier();
        cur ^= 1;
    }
    asm volatile("s_waitcnt vmcnt(0)" ::: "memory");  // retire wrapped dummy stages

    // partial epilogue (r16-validated): fp32 acc + per-query lsum to workspace
    int qt = qg * 4 + wv;                 // 32-q tile index 0..63
    int w = (bh * 64 + qt) * 2 + kh;
    float* pa = pacc + (size_t)w * 1024;  // [32 q][32 d]
#pragma unroll
    for (int nj = 0; nj < 2; ++nj) {
#pragma unroll
        for (int dj = 0; dj < 2; ++dj)
            *(f32x4*)(pa + (16 * nj + ll) * 32 + 16 * dj + 4 * hi) = acc[nj][dj];
        lsum[nj] += __shfl_xor(lsum[nj], 16);
        lsum[nj] += __shfl_xor(lsum[nj], 32);
        if (hi == 0) plsum[w * 32 + 16 * nj + ll] = lsum[nj];
    }
}

// ---------------------------------------------------------------------------
// Combine split-K halves (r16-validated, verbatim): out=(a0+a1)/(l0+l1) -> h2T.
// ---------------------------------------------------------------------------
__global__ __launch_bounds__(256) void attn_combine(const float* __restrict__ pacc,
                                                    const float* __restrict__ plsum,
                                                    unsigned short* __restrict__ h2T) {
    int idx = blockIdx.x * 256 + threadIdx.x;   // 0..65535
    int bh = idx >> 11, rem = idx & 2047;       // rem = n
    int b = bh >> 3, h = bh & 7;
    int qt = rem >> 5, q = rem & 31;
    int w0 = (bh * 64 + qt) * 2;
    const float* a0 = pacc + (size_t)w0 * 1024 + q * 32;
    const float* a1 = a0 + 1024;
    float inv = 1.f / (plsum[w0 * 32 + q] + plsum[w0 * 32 + 32 + q]);
    unsigned short* ob = h2T + ((size_t)b * kL + rem) * kC + h * 32;
#pragma unroll
    for (int dd = 0; dd < 4; ++dd) {
        float4 x0 = *(const float4*)(a0 + dd * 8);
        float4 x1 = *(const float4*)(a1 + dd * 8);
        float4 y0 = *(const float4*)(a0 + dd * 8 + 4);
        float4 y1 = *(const float4*)(a1 + dd * 8 + 4);
        *(uint4*)(ob + dd * 8) = make_uint4(
            cvt_pk((x0.x + x1.x) * inv, (x0.y + x1.y) * inv),
            cvt_pk((x0.z + x1.z) * inv, (x0.w + x1.w) * inv),
            cvt_pk((y0.x + y1.x) * inv, (y0.y + y1.y) * inv),
            cvt_pk((y0.z + y1.z) * inv, (y0.w + y1.w) * inv));
    }
}

// ---------------------------------------------------------------------------
// OUT GEMM v2 (r18, unchanged): staged-B pipeline, bias+residual, fp32 out.
// ---------------------------------------------------------------------------
__global__ __launch_bounds__(256) void out_gemm(const unsigned short* __restrict__ Wb,
                                                const unsigned short* __restrict__ h2T,
                                                const float* __restrict__ outb,
                                                const float* __restrict__ x,
                                                float* __restrict__ out) {
    __shared__ alignas(16) unsigned short Hlds[2][8][512];
    int t = threadIdx.x, wv = t >> 6, ll = t & 15, lg = (t >> 4) & 3;
    int lane = t & 63;
    int n0 = blockIdx.x * 128, o0 = blockIdx.y * 64, b = blockIdx.z;
    int obase = o0 + wv * 16;
    const unsigned short* hb = h2T + (size_t)b * kL * kC;

    bf16x8 wf[8];
#pragma unroll
    for (int k = 0; k < 8; ++k)
        wf[k] = *(const bf16x8*)(Wb + (size_t)(obase + ll) * 256 + 32 * k + 8 * lg);
    float bias[4];
#pragma unroll
    for (int r = 0; r < 4; ++r) bias[r] = outb[obase + 4 * lg + r];

    const unsigned short* hsrc0 = hb + (size_t)(n0 + 16 * (2 * wv)     + ll) * 256 + 8 * lg;
    const unsigned short* hsrc1 = hb + (size_t)(n0 + 16 * (2 * wv + 1) + ll) * 256 + 8 * lg;

    glds16(hsrc0,      &Hlds[0][2 * wv][0]);
    glds16(hsrc1,      &Hlds[0][2 * wv + 1][0]);
    glds16(hsrc0 + 32, &Hlds[1][2 * wv][0]);
    glds16(hsrc1 + 32, &Hlds[1][2 * wv + 1][0]);
    asm volatile("s_waitcnt vmcnt(2)" ::: "memory");
    __builtin_amdgcn_sched_barrier(0);
    __builtin_amdgcn_s_barrier();

    f32x4 acc[8] = {};
    int cur = 0;
    for (int c = 0; c < 8; ++c) {
        bf16x8 hf[8];
#pragma unroll
        for (int nj = 0; nj < 8; ++nj)
            hf[nj] = *(const bf16x8*)&Hlds[cur][nj][lane * 8];
        asm volatile("s_waitcnt lgkmcnt(0)" ::: "memory");
        __builtin_amdgcn_sched_barrier(0);
        __builtin_amdgcn_s_barrier();

        int kn = ((c + 2) & 7) * 32;
        glds16(hsrc0 + kn, &Hlds[cur][2 * wv][0]);
        glds16(hsrc1 + kn, &Hlds[cur][2 * wv + 1][0]);

        __builtin_amdgcn_s_setprio(1);
#pragma unroll
        for (int nj = 0; nj < 8; ++nj)
            acc[nj] = mfma16(wf[c], hf[nj], acc[nj]);
        __builtin_amdgcn_s_setprio(0);

        asm volatile("s_waitcnt vmcnt(2)" ::: "memory");
        __builtin_amdgcn_sched_barrier(0);
        __builtin_amdgcn_s_barrier();
        cur ^= 1;
    }
    asm volatile("s_waitcnt vmcnt(0)" ::: "memory");

#pragma unroll
    for (int nj = 0; nj < 8; ++nj) {
        int n = n0 + 16 * nj + ll;
#pragma unroll
        for (int r = 0; r < 4; ++r) {
            size_t row = (size_t)b * kC + obase + 4 * lg + r;
            out[row * kL + n] = acc[nj][r] + bias[r] + x[row * kL + n];
        }
    }
}

// ---------------------------------------------------------------------------
extern "C" void kernel_launch(void* const* d_in, const int* in_sizes, int n_in,
                              void* d_out, int out_size, void* d_ws, size_t ws_size,
                              hipStream_t stream) {
    const float* x     = (const float*)d_in[0];
    const float* gn_w  = (const float*)d_in[1];
    const float* gn_b  = (const float*)d_in[2];
    const float* qkv_w = (const float*)d_in[3];
    const float* qkv_b = (const float*)d_in[4];
    const float* out_w = (const float*)d_in[5];
    const float* out_b = (const float*)d_in[6];
    float* out = (float*)d_out;

    char* ws = (char*)d_ws;
    const size_t MB = 1024 * 1024;
    unsigned short* hT   = (unsigned short*)(ws);             // 0-4 MB
    unsigned short* qT   = (unsigned short*)(ws + 4  * MB);   // 4-8 MB
    unsigned short* kT   = (unsigned short*)(ws + 8  * MB);   // 8-12 MB
    unsigned short* vbuf = (unsigned short*)(ws + 12 * MB);   // 12-16 MB
    unsigned short* h2T  = (unsigned short*)(ws + 16 * MB);   // 16-20 MB
    unsigned short* wqkv = (unsigned short*)(ws + 20 * MB);   // 20-20.375 MB
    unsigned short* wout = (unsigned short*)(ws + 20 * MB + 512 * 1024);
    float* pacc  = (float*)(ws + 21 * MB);                    // 21-37 MB
    float* plsum = (float*)(ws + 37 * MB);                    // 37-37.5 MB

    gncvt_kernel<<<dim3(384), 256, 0, stream>>>(x, gn_w, gn_b, hT, qkv_w, out_w, wqkv, wout);
    qkv_gemm<<<dim3(16, 12, kB), 256, 0, stream>>>(wqkv, hT, qkv_b, qT, kT, vbuf);
    attn_kernel<<<dim3(1024), 256, 0, stream>>>(qT, kT, vbuf, pacc, plsum);
    attn_combine<<<dim3(256), 256, 0, stream>>>(pacc, plsum, h2T);
    out_gemm<<<dim3(16, 4, kB), 256, 0, stream>>>(wout, h2T, out_b, x, out);
}